// Round 9
// baseline (232.543 us; speedup 1.0000x reference)
//
#include <hip/hip_runtime.h>
#include <hip/hip_bf16.h>

// MultiHeadedAttention2: dual-stream MHA with elementwise-max merge of the two
// softmax attention maps. Inputs fp32 (detected & converted to bf16 in ws);
// internal compute bf16 MFMA; OUTPUT WRITTEN AS FP32 (reference output dtype).
//
// Pipeline (4 dispatches):
//  0) convert_inputs: dtype-probe + convert/copy to bf16 in ws (8192 chunks).
//  1) qkv_gemm : 6 projections. Q,K -> [B,H,S,64] bf16, V -> [B,H,64,S] bf16.
//                XCD-chunked 1-D grid; 3-buffer counted-vmcnt mainloop.
//                *** R9: LDS XOR-swizzle (src-side, rule #21) kills the
//                8-way frag-read bank conflict the loop had since R0. ***
//  2) attn_merged v6: v5 structure (QB=128, 2 q-subtiles/wave, swapped QK
//                with permuted K rows -> P packed as 16x16x32 PV A-frag),
//                KVB 32 -> 64: halves iteration count -> halves the
//                per-iteration overhead term (~33us of 71.6) at identical
//                per-key LDS/MFMA/exp2 work and identical summation order.
//  3) out_gemm : output projections + bias -> d_out (FP32), XCD-chunked grid.

typedef unsigned short u16;
typedef __attribute__((ext_vector_type(8))) short short8;   // 8 x bf16 (4 VGPRs)
typedef __attribute__((ext_vector_type(4))) short s4pack;   // 4 x bf16 (8 B)
typedef __attribute__((ext_vector_type(4))) float floatx4;  // MFMA accumulator

#define B_DIM 8
#define S_DIM 1024
#define H_DIM 8
#define DK 64
#define DMODEL 512
#define NTOK (B_DIM * S_DIM)                 // 8192 tokens
#define SEG ((size_t)NTOK * DMODEL)          // 4194304 elems per tensor
#define WSEG ((size_t)DMODEL * DMODEL)       // 262144 elems per weight

#define SCHED_FENCE() __builtin_amdgcn_sched_barrier(0)
#define LGKM0() asm volatile("s_waitcnt lgkmcnt(0)" ::: "memory")
#define BARRIER() __builtin_amdgcn_s_barrier()

__device__ __forceinline__ floatx4 mfma_bf16(short8 a, short8 b, floatx4 c) {
  return __builtin_amdgcn_mfma_f32_16x16x32_bf16(a, b, c, 0, 0, 0);
}

__device__ __forceinline__ u16 f32_to_bf16_rne(float f) {
  unsigned u = __float_as_uint(f);
  unsigned r = u + 0x7FFFu + ((u >> 16) & 1u);
  return (u16)(r >> 16);
}

__device__ __forceinline__ float bf16_bits_to_f32(u16 u) {
  return __uint_as_float(((unsigned)u) << 16);
}

// async global->LDS, 16B per lane; lds is the wave-uniform base
// (HW deposits lane i at lds + i*16).
__device__ __forceinline__ void async_cp16(const u16* g, u16* lds) {
  __builtin_amdgcn_global_load_lds(
      (__attribute__((address_space(1))) void*)(const_cast<u16*>(g)),
      (__attribute__((address_space(3))) void*)(lds), 16, 0, 0);
}

// ---------------------------------------------------------------------------
// Kernel 0: dtype-detect + convert to bf16. 8192-elem chunks, 4 iters each.
// ---------------------------------------------------------------------------
#define NT_CONV 18
#define CCHUNK 8192
struct ConvParams {
  const void* src[NT_CONV];
  u16* dst[NT_CONV];
  int n[NT_CONV];
  int coff[NT_CONV + 1];   // prefix sums of chunk counts
};

__global__ __launch_bounds__(256) void convert_inputs(ConvParams p) {
  __shared__ int flag_f32;
  const int blk = blockIdx.x;
  int t = 0;
  while (t + 1 < NT_CONV && blk >= p.coff[t + 1]) ++t;
  const int lc = blk - p.coff[t];
  const int n = p.n[t];
  const int tid = threadIdx.x;

  if (tid < 64) {
    const u16* s = (const u16*)p.src[t];
    int bad = 0;
#pragma unroll
    for (int j = 0; j < 8; ++j) {
      float f = bf16_bits_to_f32(s[tid * 8 + j]);
      bad |= !(fabsf(f) < 1e4f);   // catches huge AND NaN
    }
    bad |= __shfl_xor(bad, 1);
    bad |= __shfl_xor(bad, 2);
    bad |= __shfl_xor(bad, 4);
    bad |= __shfl_xor(bad, 8);
    bad |= __shfl_xor(bad, 16);
    bad |= __shfl_xor(bad, 32);
    if (tid == 0) flag_f32 = bad;
  }
  __syncthreads();
  const int is_f32 = flag_f32;
  const int base = lc * CCHUNK;

#pragma unroll
  for (int it = 0; it < CCHUNK / 2048; ++it) {
    const int idx = base + (it * 256 + tid) * 8;
    if (idx + 8 > n) break;
    if (!is_f32) {
      *(short8*)&p.dst[t][idx] = *(const short8*)&((const u16*)p.src[t])[idx];
    } else {
      const float* s = (const float*)p.src[t] + idx;
      short8 o;
#pragma unroll
      for (int j = 0; j < 8; ++j) o[j] = (short)f32_to_bf16_rne(s[j]);
      *(short8*)&p.dst[t][idx] = o;
    }
  }
}

// ---------------------------------------------------------------------------
// 128x128 NT GEMM mainloop, 3-buffer counted-vmcnt pipeline.
// LDS layout swizzled via PRE-SWIZZLED GLOBAL SOURCE (rule #21: the
// global_load_lds deposit is linear, so slot (row,ch) is filled with global
// chunk ch ^ s(row), s(row) = (row>>1)&3). Frag reads XOR the chunk with the
// same s(row) -> conflict drops 8-way -> 2-way (free, m136). Bitwise-
// identical results (pure layout permutation).
// ---------------------------------------------------------------------------
__device__ __forceinline__ void gemm128_mainloop(
    const u16* __restrict__ A, const u16* __restrict__ W,
    int m0, int n0, u16* ldsA, u16* ldsB, floatx4 acc[4][4]) {
  const int tid = threadIdx.x;
  const int lane = tid & 63;
  const int wid = tid >> 6;
  const int wm = wid >> 1, wn = wid & 1;
  const int r = lane & 15, g = lane >> 4;

  const int stg_row = wid * 32 + (lane >> 2);
  // pre-swizzled source column: chunk (lane&3) ^ s(stg_row); s = (row>>1)&3
  // = (lane>>3)&3 here (wid*32 contributes 0 mod 4; +16 rows also invariant).
  const int stg_col = (((lane & 3) ^ ((lane >> 3) & 3)) * 8);

  const u16* ga0 = A + (size_t)(m0 + stg_row) * DMODEL + stg_col;
  const u16* ga1 = A + (size_t)(m0 + stg_row + 16) * DMODEL + stg_col;
  const u16* gb0 = W + (size_t)(n0 + stg_row) * DMODEL + stg_col;
  const u16* gb1 = W + (size_t)(n0 + stg_row + 16) * DMODEL + stg_col;
  const int lo0 = (wid * 32) * 32;        // wave-uniform LDS offsets
  const int lo1 = (wid * 32 + 16) * 32;

  // prologue: tiles 0..2 -> bufs 0..2 (12 loads/wave in flight)
#pragma unroll
  for (int t = 0; t < 3; ++t) {
    const int nb = t * 4096;
    const int ko = t * 32;
    async_cp16(ga0 + ko, ldsA + nb + lo0);
    async_cp16(ga1 + ko, ldsA + nb + lo1);
    async_cp16(gb0 + ko, ldsB + nb + lo0);
    async_cp16(gb1 + ko, ldsB + nb + lo1);
  }

  // swizzled read chunk: g ^ s(row); s(row) = (row>>1)&3 = (r>>1)&3 for all
  // frag rows (wm*64 + i*16 contribute 0 mod 8 -> row>>1 ≡ r>>1 mod 4).
  const int rc = ((g ^ ((r >> 1) & 3)) * 8);

#pragma unroll
  for (int kt = 0; kt < 16; ++kt) {
    SCHED_FENCE();
    if (kt < 14)       asm volatile("s_waitcnt vmcnt(8)" ::: "memory");
    else if (kt == 14) asm volatile("s_waitcnt vmcnt(4)" ::: "memory");
    else               asm volatile("s_waitcnt vmcnt(0)" ::: "memory");
    BARRIER();
    SCHED_FENCE();

    const int cb = (kt % 3) * 4096;
    short8 a[4], b[4];
#pragma unroll
    for (int i = 0; i < 4; ++i)
      a[i] = *(const short8*)&ldsA[cb + (wm * 64 + i * 16 + r) * 32 + rc];
#pragma unroll
    for (int j = 0; j < 4; ++j)
      b[j] = *(const short8*)&ldsB[cb + (wn * 64 + j * 16 + r) * 32 + rc];
#pragma unroll
    for (int i = 0; i < 4; ++i)
#pragma unroll
      for (int j = 0; j < 4; ++j)
        acc[i][j] = mfma_bf16(a[i], b[j], acc[i][j]);

    if (kt + 3 < 16) {
      SCHED_FENCE(); BARRIER(); SCHED_FENCE();
      const int ko = (kt + 3) * 32;
      async_cp16(ga0 + ko, ldsA + cb + lo0);
      async_cp16(ga1 + ko, ldsA + cb + lo1);
      async_cp16(gb0 + ko, ldsB + cb + lo0);
      async_cp16(gb1 + ko, ldsB + cb + lo1);
    }
  }
}

// ---------------------------------------------------------------------------
// Kernel 1: QKV projections. 1-D grid = 1536, XCD-chunked, m-major per chunk.
// ---------------------------------------------------------------------------
struct QkvParams {
  const u16* X[2];
  const u16* W[2][3];
  const u16* Bias[2][3];
  u16* Out[2][3];
};

__global__ __launch_bounds__(256) void qkv_gemm(QkvParams p) {
  __shared__ u16 ldsA[3 * 128 * 32];
  __shared__ u16 ldsB[3 * 128 * 32];
  const int lin = blockIdx.x;
  const int wg = (lin & 7) * 192 + (lin >> 3);   // bijective (1536 = 8*192)
  const int m0 = (wg / 24) * 128;
  const int c = wg % 24;
  const int z = c / 12;
  const int yc = c % 12;
  const int wi = yc >> 2;                        // 0=Q 1=K 2=V
  const int n0 = (yc & 3) * 128;

  floatx4 acc[4][4];
  const floatx4 z4 = {0.f, 0.f, 0.f, 0.f};
#pragma unroll
  for (int i = 0; i < 4; ++i)
#pragma unroll
    for (int j = 0; j < 4; ++j) acc[i][j] = z4;

  gemm128_mainloop(p.X[z], p.W[z][wi], m0, n0, ldsA, ldsB, acc);

  const int tid = threadIdx.x, lane = tid & 63, wid = tid >> 6;
  const int wm = wid >> 1, wn = wid & 1, r = lane & 15, g = lane >> 4;
  const u16* bias = p.Bias[z][wi];
  u16* out = p.Out[z][wi];
  const float qscale = 0.125f * 1.4426950408889634f;  // 1/sqrt(dk) * log2(e)

#pragma unroll
  for (int j = 0; j < 4; ++j) {
    const int cc = n0 + wn * 64 + j * 16 + r;         // output col in [0,512)
    const float bv = bf16_bits_to_f32(bias[cc]);
    const int h = cc >> 6, d = cc & 63;
#pragma unroll
    for (int i = 0; i < 4; ++i) {
      const int row0 = m0 + wm * 64 + i * 16 + g * 4; // 4 consecutive tokens
      const int bb = row0 >> 10, ss0 = row0 & 1023;
      if (wi == 2) {
        // V^T: [B,H,64,S]. 4 consecutive ss at fixed d -> one 8B store.
        s4pack pk;
#pragma unroll
        for (int ii = 0; ii < 4; ++ii)
          pk[ii] = (short)f32_to_bf16_rne(acc[i][j][ii] + bv);
        *(s4pack*)&out[(((size_t)(bb * H_DIM + h)) * DK + d) * S_DIM + ss0] = pk;
      } else {
#pragma unroll
        for (int ii = 0; ii < 4; ++ii) {
          float v = acc[i][j][ii] + bv;
          if (wi == 0) v *= qscale;                   // Q: pre-scaled
          out[(((size_t)(bb * H_DIM + h)) * S_DIM + (ss0 + ii)) * DK + d] =
              f32_to_bf16_rne(v);
        }
      }
    }
  }
}

// ---------------------------------------------------------------------------
// Kernel 2 v6: merged-softmax attention. grid = 512 (64 bh x 4 q-tiles of
// QB=128), XCD-chunked swizzle. Wave w owns q rows [q0 + w*32, +32) as two
// 16-row subtiles (mt). KVB=64 processed as two 32-key sub-blocks per iter:
// identical per-key work to v5, HALF the barriers/staging-latency exposure.
// ---------------------------------------------------------------------------
#define KVB 64
#define QB 128

struct AttnParams {
  const u16* Q[2];
  const u16* K[2];
  const u16* Vt[2];
  u16* O[2];
};

__global__ __launch_bounds__(256, 2) void attn_merged(AttnParams p) {
  __shared__ u16 Ks[2][KVB * 64];   // [stream][key][d], chunk-swizzled (sK)
  __shared__ u16 Vs[2][64 * KVB];   // [stream][d][key], chunk-swizzled (sV)

  const int tid = threadIdx.x;
  const int lane = tid & 63;
  const int wid = tid >> 6;
  const int r = lane & 15, g = lane >> 4;

  // XCD-chunked bijective swizzle (512 = 8 XCD * 64): 8 whole heads per XCD.
  const int lin = blockIdx.x;
  const int w = (lin & 7) * 64 + (lin >> 3);
  const int bh = w >> 3;                 // (b*8+h)
  const int q0 = (w & 7) * QB;           // q-tile base
  const size_t hbase = (size_t)bh * S_DIM * DK;

  // K staging: 2 ops/stream: key-rows (tid>>3) and +32, d-chunk tid&7.
  // Chunk slot XOR-swizzled by sK(row) = (row&3)|(((row>>3)&1)<<2)
  // (invariant under row+32, so both ops share sK).
  const int krow = tid >> 3, kch = tid & 7;
  const int sK = (krow & 3) | (((krow >> 3) & 1) << 2);
  const int kdst0 = krow * 64 + ((kch ^ sK) * 8);
  const int kdst1 = (krow + 32) * 64 + ((kch ^ sK) * 8);
  const size_t kg0 = (size_t)krow * DK + kch * 8;
  const size_t kg1 = kg0 + (size_t)32 * DK;

  // V staging: 2 ops/stream: d-rows (tid>>3) and +32, key-chunk tid&7.
  // sV(row) = row&7 (invariant under row+32).
  const int vrow = tid >> 3, vch = tid & 7;
  const int sV = vrow & 7;
  const int vdst0 = vrow * KVB + ((vch ^ sV) * 8);
  const int vdst1 = (vrow + 32) * KVB + ((vch ^ sV) * 8);
  const size_t vg0 = (size_t)vrow * S_DIM + vch * 8;
  const size_t vg1 = vg0 + (size_t)32 * S_DIM;

  // Permuted K-frag constants (per 32-key sub-block kb):
  // A-half rows kb*32 + (r>>2)*8+(r&3), B-half +4; swizzle value srg is
  // invariant across kb and halves.
  const int srg = (r & 3) | (((r >> 2) & 1) << 2);
  const int prow = ((r >> 2) * 8 + (r & 3)) * 64;
  const int cA0 = (g ^ srg) * 8;
  const int cA1 = ((4 + g) ^ srg) * 8;

  // Q fragments (B-operand): lane holds Q[q=q0+wid*32+mt*16+r][d=kc*32+g*8+j]
  short8 qf[2][2][2];
#pragma unroll
  for (int s = 0; s < 2; ++s)
#pragma unroll
    for (int mt = 0; mt < 2; ++mt)
#pragma unroll
      for (int kc = 0; kc < 2; ++kc)
        qf[s][mt][kc] = *(const short8*)
            &p.Q[s][hbase + (size_t)(q0 + wid * 32 + mt * 16 + r) * DK +
                    kc * 32 + g * 8];

  // tile-0 K prefetch
  short8 kst[2][2], vst[2][2];
#pragma unroll
  for (int s = 0; s < 2; ++s) {
    kst[s][0] = *(const short8*)&p.K[s][hbase + kg0];
    kst[s][1] = *(const short8*)&p.K[s][hbase + kg1];
  }

  const floatx4 z4 = {0.f, 0.f, 0.f, 0.f};
  float sl[2][2] = {{0.f, 0.f}, {0.f, 0.f}};   // [s][mt] 2^score sums, q=r

  // ---- pass 1: per-q sums of 2^score for both streams ----
  for (int kt = 0; kt < 16; ++kt) {
    if (kt) { SCHED_FENCE(); BARRIER(); SCHED_FENCE(); }
#pragma unroll
    for (int s = 0; s < 2; ++s) {     // implicit counted vmcnt on kst only
      *(short8*)&Ks[s][kdst0] = kst[s][0];
      *(short8*)&Ks[s][kdst1] = kst[s][1];
    }
    if (kt < 15) {
      const size_t k0n = (size_t)(kt + 1) * KVB * DK;
#pragma unroll
      for (int s = 0; s < 2; ++s) {
        kst[s][0] = *(const short8*)&p.K[s][hbase + k0n + kg0];
        kst[s][1] = *(const short8*)&p.K[s][hbase + k0n + kg1];
      }
    }
    SCHED_FENCE(); LGKM0(); BARRIER(); SCHED_FENCE();

#pragma unroll
    for (int kb = 0; kb < 2; ++kb) {
      const int ro = kb * 2048 + prow;
#pragma unroll
      for (int s = 0; s < 2; ++s) {
        const short8 kA0 = *(const short8*)&Ks[s][ro + cA0];
        const short8 kA1 = *(const short8*)&Ks[s][ro + cA1];
        const short8 kB0 = *(const short8*)&Ks[s][ro + 256 + cA0];
        const short8 kB1 = *(const short8*)&Ks[s][ro + 256 + cA1];
#pragma unroll
        for (int mt = 0; mt < 2; ++mt) {
          floatx4 aA = mfma_bf16(kA0, qf[s][mt][0], z4);
          aA = mfma_bf16(kA1, qf[s][mt][1], aA);
          floatx4 aB = mfma_bf16(kB0, qf[s][mt][0], z4);
          aB = mfma_bf16(kB1, qf[s][mt][1], aB);
          sl[s][mt] += __builtin_amdgcn_exp2f(aA[0]) + __builtin_amdgcn_exp2f(aA[1]) +
                       __builtin_amdgcn_exp2f(aA[2]) + __builtin_amdgcn_exp2f(aA[3]) +
                       __builtin_amdgcn_exp2f(aB[0]) + __builtin_amdgcn_exp2f(aB[1]) +
                       __builtin_amdgcn_exp2f(aB[2]) + __builtin_amdgcn_exp2f(aB[3]);
        }
      }
    }
  }

  // pass-2 tile-0 staged loads: issued now so they fly under the reduction
#pragma unroll
  for (int s = 0; s < 2; ++s) {
    kst[s][0] = *(const short8*)&p.K[s][hbase + kg0];
    kst[s][1] = *(const short8*)&p.K[s][hbase + kg1];
    vst[s][0] = *(const short8*)&p.Vt[s][hbase + vg0];
    vst[s][1] = *(const short8*)&p.Vt[s][hbase + vg1];
  }

  // reduce over g (key groups); lane keeps the total for its q=r.
  float inv_[2][2];
#pragma unroll
  for (int s = 0; s < 2; ++s)
#pragma unroll
    for (int mt = 0; mt < 2; ++mt) {
      float v = sl[s][mt];
      v += __shfl_xor(v, 16);
      v += __shfl_xor(v, 32);
      inv_[s][mt] = 1.0f / v;
    }

  floatx4 o_[2][2][4];   // [s][mt][nt(d)] : lane holds O[q=mt*16+g*4+i][d=nt*16+r]
#pragma unroll
  for (int s = 0; s < 2; ++s)
#pragma unroll
    for (int mt = 0; mt < 2; ++mt)
#pragma unroll
      for (int nt = 0; nt < 4; ++nt) o_[s][mt][nt] = z4;

  // ---- pass 2: recompute scores, p = max(softmax_r, softmax_f), O += P@V ----
  for (int kt = 0; kt < 16; ++kt) {
    // kt==0 barrier also closes pass-1's last readers of Ks
    SCHED_FENCE(); BARRIER(); SCHED_FENCE();
#pragma unroll
    for (int s = 0; s < 2; ++s) {
      *(short8*)&Ks[s][kdst0] = kst[s][0];
      *(short8*)&Ks[s][kdst1] = kst[s][1];
      *(short8*)&Vs[s][vdst0] = vst[s][0];
      *(short8*)&Vs[s][vdst1] = vst[s][1];
    }
    if (kt < 15) {
      const size_t knk = (size_t)(kt + 1) * KVB;
#pragma unroll
      for (int s = 0; s < 2; ++s) {
        kst[s][0] = *(const short8*)&p.K[s][hbase + knk * DK + kg0];
        kst[s][1] = *(const short8*)&p.K[s][hbase + knk * DK + kg1];
        vst[s][0] = *(const short8*)&p.Vt[s][hbase + vg0 + knk];
        vst[s][1] = *(const short8*)&p.Vt[s][hbase + vg1 + knk];
      }
    }
    SCHED_FENCE(); LGKM0(); BARRIER(); SCHED_FENCE();

#pragma unroll
    for (int kb = 0; kb < 2; ++kb) {
      const int ro = kb * 2048 + prow;
      // K-frags once (permuted rows), reused for both q-subtiles.
      short8 kA0[2], kA1[2], kB0[2], kB1[2];
#pragma unroll
      for (int s = 0; s < 2; ++s) {
        kA0[s] = *(const short8*)&Ks[s][ro + cA0];
        kA1[s] = *(const short8*)&Ks[s][ro + cA1];
        kB0[s] = *(const short8*)&Ks[s][ro + 256 + cA0];
        kB1[s] = *(const short8*)&Ks[s][ro + 256 + cA1];
      }

      // QK (swapped, permuted) + merged softmax -> packed PV A-frag per mt:
      // pA[mt] holds P[q=r][key = kb*32 + g*8 + j], j=0..7.
      short8 pA[2];
#pragma unroll
      for (int mt = 0; mt < 2; ++mt) {
        floatx4 arA = mfma_bf16(kA0[0], qf[0][mt][0], z4);
        arA = mfma_bf16(kA1[0], qf[0][mt][1], arA);
        floatx4 arB = mfma_bf16(kB0[0], qf[0][mt][0], z4);
        arB = mfma_bf16(kB1[0], qf[0][mt][1], arB);
        floatx4 afA = mfma_bf16(kA0[1], qf[1][mt][0], z4);
        afA = mfma_bf16(kA1[1], qf[1][mt][1], afA);
        floatx4 afB = mfma_bf16(kB0[1], qf[1][mt][0], z4);
        afB = mfma_bf16(kB1[1], qf[1][mt][1], afB);
#pragma unroll
        for (int i = 0; i < 4; ++i) {
          const float prA = __builtin_amdgcn_exp2f(arA[i]) * inv_[0][mt];
          const float pfA = __builtin_amdgcn_exp2f(afA[i]) * inv_[1][mt];
          pA[mt][i] = (short)f32_to_bf16_rne(fmaxf(prA, pfA));
          const float prB = __builtin_amdgcn_exp2f(arB[i]) * inv_[0][mt];
          const float pfB = __builtin_amdgcn_exp2f(afB[i]) * inv_[1][mt];
          pA[mt][4 + i] = (short)f32_to_bf16_rne(fmaxf(prB, pfB));
        }
      }

      // V B-frags once (b128), reused for both q-subtiles:
      // B[k=key kb*32+g*8+j][n=d=r] = Vs[d-row nt*16+r][key-chunk kb*4+g].
      short8 vB[2][4];
#pragma unroll
      for (int s = 0; s < 2; ++s)
#pragma unroll
        for (int nt = 0; nt < 4; ++nt)
          vB[s][nt] = *(const short8*)
              &Vs[s][(nt * 16 + r) * KVB + (((kb * 4 + g) ^ (r & 7)) * 8)];

#pragma unroll
      for (int s = 0; s < 2; ++s)
#pragma unroll
        for (int mt = 0; mt < 2; ++mt)
#pragma unroll
          for (int nt = 0; nt < 4; ++nt)
            o_[s][mt][nt] = mfma_bf16(pA[mt], vB[s][nt], o_[s][mt][nt]);
    }
  }

  // write O: [B,S,512] bf16. lane holds O[q = mt*16+g*4+i][d = nt*16+r].
  const int bb = bh >> 3, h = bh & 7;
#pragma unroll
  for (int s = 0; s < 2; ++s) {
    u16* out = p.O[s];
#pragma unroll
    for (int mt = 0; mt < 2; ++mt)
#pragma unroll
      for (int nt = 0; nt < 4; ++nt) {
        const int col = h * 64 + nt * 16 + r;
#pragma unroll
        for (int i = 0; i < 4; ++i) {
          const int row = q0 + wid * 32 + mt * 16 + g * 4 + i;
          out[((size_t)bb * S_DIM + row) * DMODEL + col] =
              f32_to_bf16_rne(o_[s][mt][nt][i]);
        }
      }
  }
}

// ---------------------------------------------------------------------------
// Kernel 3: output projections. 1-D grid = 512, XCD-chunked, m-major.
// ---------------------------------------------------------------------------
struct OutParams {
  const u16* A[2];
  const u16* W[2];
  const u16* Bias[2];
  float* Out[2];
};

__global__ __launch_bounds__(256) void out_gemm(OutParams p) {
  __shared__ u16 ldsA[3 * 128 * 32];
  __shared__ u16 ldsB[3 * 128 * 32];
  const int lin = blockIdx.x;
  const int wg = (lin & 7) * 64 + (lin >> 3);   // bijective (512 = 8*64)
  const int m0 = (wg >> 3) * 128;
  const int c = wg & 7;
  const int z = c >> 2;
  const int n0 = (c & 3) * 128;

  floatx4 acc[4][4];
  const floatx4 z4 = {0.f, 0.f, 0.f, 0.f};
#pragma unroll
  for (int i = 0; i < 4; ++i)
#pragma unroll
    for (int j = 0; j < 4; ++j) acc[i][j] = z4;

  gemm128_mainloop(p.A[z], p.W[z], m0, n0, ldsA, ldsB, acc);

  const int tid = threadIdx.x, lane = tid & 63, wid = tid >> 6;
  const int wm = wid >> 1, wn = wid & 1, r = lane & 15, g = lane >> 4;
  const u16* bias = p.Bias[z];
  float* out = p.Out[z];

#pragma unroll
  for (int j = 0; j < 4; ++j) {
    const int cc = n0 + wn * 64 + j * 16 + r;
    const float bv = bf16_bits_to_f32(bias[cc]);
#pragma unroll
    for (int i = 0; i < 4; ++i) {
      const int row0 = m0 + wm * 64 + i * 16 + g * 4;
#pragma unroll
      for (int ii = 0; ii < 4; ++ii)
        out[(size_t)(row0 + ii) * DMODEL + cc] = acc[i][j][ii] + bv;   // FP32
    }
  }
}

// ---------------------------------------------------------------------------
extern "C" void kernel_launch(void* const* d_in, const int* in_sizes, int n_in,
                              void* d_out, int out_size, void* d_ws, size_t ws_size,
                              hipStream_t stream) {
  (void)in_sizes; (void)n_in; (void)out_size; (void)ws_size;
  u16* ws = (u16*)d_ws;
  u16* Qr = ws + 0 * SEG;
  u16* Kr = ws + 1 * SEG;
  u16* Vr = ws + 2 * SEG;   // stored transposed [B,H,64,S]
  u16* Qf = ws + 3 * SEG;
  u16* Kf = ws + 4 * SEG;
  u16* Vf = ws + 5 * SEG;   // stored transposed [B,H,64,S]
  u16* Or = ws + 6 * SEG;   // also holds converted X_rgb before attn overwrites
  u16* Of = ws + 7 * SEG;   // also holds converted X_flow
  u16* cW = ws + 8 * SEG;            // 8 x 262144
  u16* cB = cW + 8 * WSEG;           // 8 x 512

  // ---- conversion pre-pass ----
  ConvParams cp;
  int coff = 0;
  for (int i = 0; i < NT_CONV; ++i) {
    cp.src[i] = d_in[i];
    int n;
    if (i < 2) {
      n = (int)SEG;
      cp.dst[i] = (i == 0) ? Or : Of;
    } else {
      const int k = (i - 2) >> 1;
      const int isb = (i - 2) & 1;
      n = isb ? DMODEL : (int)WSEG;
      cp.dst[i] = isb ? (cB + k * DMODEL) : (cW + k * WSEG);
    }
    cp.n[i] = n;
    cp.coff[i] = coff;
    coff += (n + CCHUNK - 1) / CCHUNK;
  }
  cp.coff[NT_CONV] = coff;   // 1288 chunks total
  convert_inputs<<<dim3(coff), dim3(256), 0, stream>>>(cp);

  // ---- QKV projections ----
  QkvParams qp;
  qp.X[0] = Or;
  qp.X[1] = Of;
  for (int s = 0; s < 2; ++s)
    for (int wi = 0; wi < 3; ++wi) {
      const int k = s * 3 + wi;
      qp.W[s][wi] = cW + k * WSEG;
      qp.Bias[s][wi] = cB + k * DMODEL;
    }
  qp.Out[0][0] = Qr; qp.Out[0][1] = Kr; qp.Out[0][2] = Vr;
  qp.Out[1][0] = Qf; qp.Out[1][1] = Kf; qp.Out[1][2] = Vf;
  qkv_gemm<<<dim3(1536), dim3(256), 0, stream>>>(qp);

  // ---- merged attention (overwrites Or/Of with O) ----
  AttnParams ap;
  ap.Q[0] = Qr; ap.Q[1] = Qf;
  ap.K[0] = Kr; ap.K[1] = Kf;
  ap.Vt[0] = Vr; ap.Vt[1] = Vf;
  ap.O[0] = Or; ap.O[1] = Of;
  attn_merged<<<dim3(512), dim3(256), 0, stream>>>(ap);

  // ---- output projections (fp32 out) ----
  OutParams op;
  op.A[0] = Or; op.A[1] = Of;
  op.W[0] = cW + 6 * WSEG; op.Bias[0] = cB + 6 * DMODEL;
  op.W[1] = cW + 7 * WSEG; op.Bias[1] = cB + 7 * DMODEL;
  op.Out[0] = (float*)d_out;
  op.Out[1] = (float*)d_out + SEG;
  out_gemm<<<dim3(512), dim3(256), 0, stream>>>(op);
}